// Round 3
// baseline (472.372 us; speedup 1.0000x reference)
//
#include <hip/hip_runtime.h>

#define IMG_H 2048
#define IMG_W 2048
#define IMG_C 8

#define KBINS      64      // 32-row slabs: 2048/64. Slab = 33 rows * 2048 px * 32 B ~= 2.1 MiB -> fits one XCD L2 (4 MiB)
#define SLAB_SHIFT 5       // i0 >> 5 -> bin
#define SPT        16      // samples per thread in scatter pass
#define SBLOCK     256

// ---------------------------------------------------------------------------
// Shared interp math (must match reference op order exactly):
//   c = max(coord - bias, 0); low = min(floor(c), H-2); d = c - low
//   mb = br + d0*(bl-br); mt = tr + d0*(tl-tr); out = mb + d1*(mt-mb)
// ---------------------------------------------------------------------------
__device__ __forceinline__ float4 lerp4(float4 tl, float4 tr, float4 bl, float4 br,
                                        float d0, float d1) {
    float4 o;
    float mb, mt;
    mb = br.x + d0 * (bl.x - br.x); mt = tr.x + d0 * (tl.x - tr.x); o.x = mb + d1 * (mt - mb);
    mb = br.y + d0 * (bl.y - br.y); mt = tr.y + d0 * (tl.y - tr.y); o.y = mb + d1 * (mt - mb);
    mb = br.z + d0 * (bl.z - br.z); mt = tr.z + d0 * (tl.z - tr.z); o.z = mb + d1 * (mt - mb);
    mb = br.w + d0 * (bl.w - br.w); mt = tr.w + d0 * (tl.w - tr.w); o.w = mb + d1 * (mt - mb);
    return o;
}

// ---------------------------------------------------------------------------
// Pass 1: bin samples by 32-row slab of i0. Per-block LDS histogram ->
// one global atomicAdd per bin per block (chunk reservation) -> scatter
// (s, cx, cy) SoA records. Overflow (statistically never, 6% margin over
// uniform) is handled by computing the answer directly -> always correct.
// ---------------------------------------------------------------------------
__global__ __launch_bounds__(SBLOCK) void scatter_kernel(
    const float* __restrict__ coords,
    const float* __restrict__ visible,
    const float* __restrict__ bias,
    float* __restrict__ out,
    unsigned* __restrict__ cursor,     // [KBINS]
    unsigned* __restrict__ recIdx,     // [KBINS*cap]
    float* __restrict__ recX,
    float* __restrict__ recY,
    int n, unsigned cap)
{
    __shared__ unsigned hist[KBINS];
    __shared__ unsigned basev[KBINS];
    __shared__ unsigned lofs[KBINS];

    int t = threadIdx.x;
    if (t < KBINS) hist[t] = 0;
    __syncthreads();

    int blockStart = blockIdx.x * (SBLOCK * SPT);
    float b0 = bias[0];
    float b1 = bias[1];

    // phase 1: LDS histogram
    for (int k = 0; k < SPT; ++k) {
        int s = blockStart + k * SBLOCK + t;        // coalesced across lanes
        if (s < n) {
            float cx = coords[2 * (size_t)s];
            float c0 = fmaxf(cx - b0, 0.0f);
            float low0 = fminf(floorf(c0), (float)(IMG_H - 2));
            int i0 = (int)low0;
            atomicAdd(&hist[i0 >> SLAB_SHIFT], 1u);
        }
    }
    __syncthreads();

    // phase 2: reserve a contiguous chunk per bin (1 global atomic/bin/block)
    if (t < KBINS) {
        basev[t] = atomicAdd(&cursor[t], hist[t]);
        lofs[t] = 0;
    }
    __syncthreads();

    // phase 3: scatter records
    for (int k = 0; k < SPT; ++k) {
        int s = blockStart + k * SBLOCK + t;
        if (s < n) {
            float2 cv = *(const float2*)(coords + 2 * (size_t)s);  // L1-hot from phase 1
            float c0 = fmaxf(cv.x - b0, 0.0f);
            float low0 = fminf(floorf(c0), (float)(IMG_H - 2));
            int i0 = (int)low0;
            int b = i0 >> SLAB_SHIFT;
            unsigned off = atomicAdd(&lofs[b], 1u);
            unsigned slot = basev[b] + off;
            if (slot < cap) {
                size_t g = (size_t)b * cap + slot;
                recIdx[g] = (unsigned)s;
                recX[g] = cv.x;
                recY[g] = cv.y;
            } else {
                // Overflow fallback: compute this sample directly (rare/never).
                float c1 = fmaxf(cv.y - b1, 0.0f);
                float low1 = fminf(floorf(c1), (float)(IMG_W - 2));
                float d0 = c0 - low0;
                float d1 = c1 - low1;
                int i1 = (int)low1;
                const float* pt = visible + ((size_t)i0 * IMG_W + (size_t)i1) * IMG_C;
                const float* pb = pt + (size_t)IMG_W * IMG_C;
                for (int q = 0; q < 2; ++q) {
                    float4 tl = *(const float4*)(pt + 4 * q);
                    float4 bl = *(const float4*)(pt + 8 + 4 * q);
                    float4 tr = *(const float4*)(pb + 4 * q);
                    float4 br = *(const float4*)(pb + 8 + 4 * q);
                    float4 o = lerp4(tl, tr, bl, br, d0, d1);
                    *(float4*)(out + (size_t)s * IMG_C + 4 * q) = o;
                }
            }
        }
    }
}

// ---------------------------------------------------------------------------
// Pass 2: process records bin-by-bin (blockIdx order ~ dispatch order), so
// the in-flight sample window touches a ~8 MiB sliding band of `visible`
// -> gathers hit L2. Two lanes per record: lane `part` handles channels
// [4p, 4p+4) so adjacent lanes load contiguous 32 B per pixel row.
// b = j / cap via exact magic multiply (j < 2^23, verified error bound).
// ---------------------------------------------------------------------------
__global__ __launch_bounds__(256) void gather_kernel(
    const float* __restrict__ visible,
    const float* __restrict__ bias,
    const unsigned* __restrict__ cursor,   // final fill counts per bin
    const unsigned* __restrict__ recIdx,
    const float* __restrict__ recX,
    const float* __restrict__ recY,
    float* __restrict__ out,
    unsigned cap, unsigned long long magicM)
{
    unsigned tid = blockIdx.x * blockDim.x + threadIdx.x;
    unsigned j = tid >> 1;
    unsigned part = tid & 1;
    if (j >= (unsigned)KBINS * cap) return;

    unsigned b = (unsigned)(((unsigned long long)j * magicM) >> 40);
    unsigned pos = j - b * cap;
    unsigned cnt = cursor[b];
    cnt = cnt > cap ? cap : cnt;
    if (pos >= cnt) return;

    unsigned s = recIdx[j];
    float cx = recX[j];
    float cy = recY[j];
    float b0 = bias[0];
    float b1 = bias[1];

    float c0 = fmaxf(cx - b0, 0.0f);
    float c1 = fmaxf(cy - b1, 0.0f);
    float low0 = fminf(floorf(c0), (float)(IMG_H - 2));
    float low1 = fminf(floorf(c1), (float)(IMG_W - 2));
    float d0 = c0 - low0;
    float d1 = c1 - low1;
    int i0 = (int)low0;
    int i1 = (int)low1;

    const float* p_t = visible + ((size_t)i0 * IMG_W + (size_t)i1) * IMG_C + part * 4;
    const float* p_b = p_t + (size_t)IMG_W * IMG_C;

    float4 tl = *(const float4*)(p_t);
    float4 bl = *(const float4*)(p_t + 8);
    float4 tr = *(const float4*)(p_b);
    float4 br = *(const float4*)(p_b + 8);

    float4 o = lerp4(tl, tr, bl, br, d0, d1);

    *(float4*)(out + (size_t)s * IMG_C + part * 4) = o;
}

// ---------------------------------------------------------------------------
// Fallback (ws too small): the previous best single-pass kernel.
// ---------------------------------------------------------------------------
__global__ __launch_bounds__(256) void idx2pixel_simple(
    const float* __restrict__ coords,
    const float* __restrict__ visible,
    const float* __restrict__ bias,
    float* __restrict__ out,
    int n)
{
    int tid = blockIdx.x * blockDim.x + threadIdx.x;
    int s = tid >> 1;
    int part = tid & 1;
    if (s >= n) return;

    float2 cv = *(const float2*)(coords + 2 * (size_t)s);
    float b0 = bias[0];
    float b1 = bias[1];

    float c0 = fmaxf(cv.x - b0, 0.0f);
    float c1 = fmaxf(cv.y - b1, 0.0f);
    float low0 = fminf(floorf(c0), (float)(IMG_H - 2));
    float low1 = fminf(floorf(c1), (float)(IMG_W - 2));
    float d0 = c0 - low0;
    float d1 = c1 - low1;
    int i0 = (int)low0;
    int i1 = (int)low1;

    const float* p_t = visible + ((size_t)i0 * IMG_W + (size_t)i1) * IMG_C + part * 4;
    const float* p_b = p_t + (size_t)IMG_W * IMG_C;

    float4 tl = *(const float4*)(p_t);
    float4 bl = *(const float4*)(p_t + 8);
    float4 tr = *(const float4*)(p_b);
    float4 br = *(const float4*)(p_b + 8);

    float4 o = lerp4(tl, tr, bl, br, d0, d1);
    *(float4*)(out + (size_t)s * IMG_C + part * 4) = o;
}

extern "C" void kernel_launch(void* const* d_in, const int* in_sizes, int n_in,
                              void* d_out, int out_size, void* d_ws, size_t ws_size,
                              hipStream_t stream) {
    const float* coords  = (const float*)d_in[0];   // (N, 2) f32
    const float* visible = (const float*)d_in[1];   // (H, W, C) f32
    const float* bias    = (const float*)d_in[2];   // (2,) f32
    float* out = (float*)d_out;                     // (N, C) f32

    int n = in_sizes[0] / 2;
    if (n <= 0) return;

    // Bin capacity: mean + 6% + 1024 slack (uniform input -> >200 sigma margin;
    // overflow is still handled correctly in scatter_kernel).
    unsigned cap = (unsigned)((unsigned long long)n / KBINS * 106ull / 100ull + 1024ull);
    size_t need = 256 + (size_t)KBINS * cap * 12;

    if (ws_size < need) {
        // Workspace too small: previous best single-pass kernel.
        long long threads = 2LL * n;
        int block = 256;
        long long grid = (threads + block - 1) / block;
        idx2pixel_simple<<<(int)grid, block, 0, stream>>>(coords, visible, bias, out, n);
        return;
    }

    unsigned* cursor = (unsigned*)d_ws;
    unsigned* recIdx = (unsigned*)((char*)d_ws + 256);
    float* recX = (float*)(recIdx + (size_t)KBINS * cap);
    float* recY = recX + (size_t)KBINS * cap;

    hipMemsetAsync(cursor, 0, KBINS * sizeof(unsigned), stream);

    int sblocks = (n + SBLOCK * SPT - 1) / (SBLOCK * SPT);
    scatter_kernel<<<sblocks, SBLOCK, 0, stream>>>(
        coords, visible, bias, out, cursor, recIdx, recX, recY, n, cap);

    // Exact unsigned division by runtime cap: b = (j*M) >> 40, M = ceil(2^40/cap).
    // Exactness: e = M*cap - 2^40 < cap; j*e < 2^23 * 2^17 = 2^40 -> floor unchanged.
    unsigned long long magicM = ((1ull << 40) + cap - 1) / cap;
    long long threads = 2LL * KBINS * (long long)cap;
    int gblocks = (int)((threads + 255) / 256);
    gather_kernel<<<gblocks, 256, 0, stream>>>(
        visible, bias, cursor, recIdx, recX, recY, out, cap, magicM);
}